// Round 1
// baseline (1892.386 us; speedup 1.0000x reference)
//
#include <hip/hip_runtime.h>
#include <hip/hip_bf16.h>
#include <math.h>

#define H_DIM 1024
#define W_DIM 512
#define VOC 32000
#define CAP_LEN 64
#define U_DIM 256
#define IMG_DIM 2048
#define XIN_DIM (IMG_DIM + U_DIM)   // 2304
#define SOS 31998
#define NBLK_LOGITS 512              // partial-argmax blocks

// ---------------- ws layout (float offsets from d_ws) ----------------
// h0 @ 0, h1 @ 1024, c0 @ 2048, c1 @ 3072       (zero-init h0/c0)
// xin @ 4096  (2304 floats: concat(img_feat, user_emb))
// x0  @ 6400  (512 floats)
// wid @ 6912  (64 int32)
// partial @ byte 27904 (512 u64)

__device__ __forceinline__ float wave_reduce_sum(float v) {
    #pragma unroll
    for (int off = 32; off > 0; off >>= 1)
        v += __shfl_xor(v, off, 64);
    return v;
}

__device__ __forceinline__ unsigned long long umax64(unsigned long long a, unsigned long long b) {
    return a > b ? a : b;
}

// zero h0/h1/c0/c1, build xin = concat(img_feat, wei_user[uid])
__global__ void k_init(const float* __restrict__ img, const int* __restrict__ uid,
                       const float* __restrict__ wei_user, float* __restrict__ wsf) {
    int i = blockIdx.x * blockDim.x + threadIdx.x;
    if (i < 4096) wsf[i] = 0.f;
    if (i < XIN_DIM) {
        float v = (i < IMG_DIM) ? img[i]
                                : wei_user[(size_t)uid[0] * U_DIM + (i - IMG_DIM)];
        wsf[4096 + i] = v;
    }
}

// x0 = WI_w @ xin + WI_b   (512 rows x 2304)
__global__ void k_x0(const float* __restrict__ WI_w, const float* __restrict__ WI_b,
                     const float* __restrict__ xin, float* __restrict__ x0) {
    int wave = threadIdx.x >> 6;
    int lane = threadIdx.x & 63;
    int row  = blockIdx.x * 4 + wave;          // grid 128 -> 512 rows
    const float* wr = WI_w + (size_t)row * XIN_DIM;
    float acc = 0.f;
    #pragma unroll
    for (int k = 0; k < 9; ++k) {              // 2304 = 9 * 256 floats
        int col = 4 * lane + 256 * k;
        float4 w4 = *reinterpret_cast<const float4*>(wr  + col);
        float4 v4 = *reinterpret_cast<const float4*>(xin + col);
        acc += w4.x * v4.x + w4.y * v4.y + w4.z * v4.z + w4.w * v4.w;
    }
    acc = wave_reduce_sum(acc);
    if (lane == 0) x0[row] = acc + WI_b[row];
}

// One LSTM step. t = -1: prime step (x = x0). t >= 0: x = word_emb[wid_{t-1}]
// (wid_{-1} = SOS). Each wave owns one h-element j and computes its 4 gate rows.
__global__ void k_lstm(int t,
                       const float* __restrict__ W_ih, const float* __restrict__ W_hh,
                       const float* __restrict__ b_ih, const float* __restrict__ b_hh,
                       const float* __restrict__ word_emb, const float* __restrict__ x0,
                       const int* __restrict__ wid_arr,
                       const float* __restrict__ h_in, const float* __restrict__ c_in,
                       float* __restrict__ h_out, float* __restrict__ c_out,
                       float* __restrict__ out_hid) {
    int wave = threadIdx.x >> 6;
    int lane = threadIdx.x & 63;
    int j = blockIdx.x * 4 + wave;             // grid 256 -> 1024 elements
    const float* x;
    if (t < 0) {
        x = x0;
    } else {
        int wid = (t == 0) ? SOS : wid_arr[t - 1];
        x = word_emb + (size_t)wid * W_DIM;
    }
    float g[4];
    #pragma unroll
    for (int gi = 0; gi < 4; ++gi) {
        int row = gi * H_DIM + j;
        const float* wi = W_ih + (size_t)row * W_DIM;
        const float* wh = W_hh + (size_t)row * H_DIM;
        float acc = 0.f;
        #pragma unroll
        for (int k = 0; k < 2; ++k) {          // 512 floats
            int col = 4 * lane + 256 * k;
            float4 w4 = *reinterpret_cast<const float4*>(wi + col);
            float4 v4 = *reinterpret_cast<const float4*>(x  + col);
            acc += w4.x * v4.x + w4.y * v4.y + w4.z * v4.z + w4.w * v4.w;
        }
        #pragma unroll
        for (int k = 0; k < 4; ++k) {          // 1024 floats
            int col = 4 * lane + 256 * k;
            float4 w4 = *reinterpret_cast<const float4*>(wh   + col);
            float4 v4 = *reinterpret_cast<const float4*>(h_in + col);
            acc += w4.x * v4.x + w4.y * v4.y + w4.z * v4.z + w4.w * v4.w;
        }
        acc = wave_reduce_sum(acc);
        g[gi] = acc + b_ih[row] + b_hh[row];
    }
    if (lane == 0) {
        float ig = 1.f / (1.f + expf(-g[0]));
        float fg = 1.f / (1.f + expf(-g[1]));
        float gg = tanhf(g[2]);
        float og = 1.f / (1.f + expf(-g[3]));
        float cn = fg * c_in[j] + ig * gg;
        float hn = og * tanhf(cn);
        c_out[j] = cn;
        h_out[j] = hn;
        if (out_hid) out_hid[j] = hn;
    }
}

// logits = WP_w @ h + WP_b; per-block partial argmax (packed key|~row).
__global__ void k_logits(const float* __restrict__ WP_w, const float* __restrict__ WP_b,
                         const float* __restrict__ h,
                         unsigned long long* __restrict__ partial) {
    int wave = threadIdx.x >> 6;
    int lane = threadIdx.x & 63;
    int wv = blockIdx.x * 4 + wave;            // 2048 waves
    unsigned long long best = 0ull;
    for (int row = wv; row < VOC; row += NBLK_LOGITS * 4) {
        const float* wr = WP_w + (size_t)row * H_DIM;
        float acc = 0.f;
        #pragma unroll
        for (int k = 0; k < 4; ++k) {          // 1024 floats
            int col = 4 * lane + 256 * k;
            float4 w4 = *reinterpret_cast<const float4*>(wr + col);
            float4 v4 = *reinterpret_cast<const float4*>(h  + col);
            acc += w4.x * v4.x + w4.y * v4.y + w4.z * v4.z + w4.w * v4.w;
        }
        acc = wave_reduce_sum(acc);
        float logit = acc + WP_b[row];
        unsigned int ub = __float_as_uint(logit);
        ub = (ub & 0x80000000u) ? ~ub : (ub | 0x80000000u);   // order-preserving map
        unsigned long long p = ((unsigned long long)ub << 32)
                             | (unsigned long long)(0xFFFFFFFFu - (unsigned)row);
        best = umax64(best, p);
    }
    __shared__ unsigned long long sm[4];
    if (lane == 0) sm[wave] = best;
    __syncthreads();
    if (threadIdx.x == 0) {
        unsigned long long m = sm[0];
        m = umax64(m, sm[1]);
        m = umax64(m, sm[2]);
        m = umax64(m, sm[3]);
        partial[blockIdx.x] = m;
    }
}

// final argmax over per-block partials; writes wid[t] and caption[t] (as float)
__global__ void k_argmax_reduce(const unsigned long long* __restrict__ partial,
                                int* __restrict__ wid_arr, int t,
                                float* __restrict__ out_cap) {
    __shared__ unsigned long long sm[256];
    int tid = threadIdx.x;
    unsigned long long best = 0ull;
    for (int i = tid; i < NBLK_LOGITS; i += 256) best = umax64(best, partial[i]);
    sm[tid] = best;
    __syncthreads();
    for (int s = 128; s > 0; s >>= 1) {
        if (tid < s) sm[tid] = umax64(sm[tid], sm[tid + s]);
        __syncthreads();
    }
    if (tid == 0) {
        unsigned long long m = sm[0];
        int row = (int)(0xFFFFFFFFu - (unsigned)(m & 0xFFFFFFFFull));
        wid_arr[t] = row;
        out_cap[t] = (float)row;
    }
}

extern "C" void kernel_launch(void* const* d_in, const int* in_sizes, int n_in,
                              void* d_out, int out_size, void* d_ws, size_t ws_size,
                              hipStream_t stream) {
    const float* img_feat = (const float*)d_in[0];
    const int*   uid      = (const int*)  d_in[1];
    const float* wei_user = (const float*)d_in[2];
    const float* WI_w     = (const float*)d_in[3];
    const float* WI_b     = (const float*)d_in[4];
    const float* WP_w     = (const float*)d_in[5];
    const float* WP_b     = (const float*)d_in[6];
    const float* W_ih     = (const float*)d_in[7];
    const float* W_hh     = (const float*)d_in[8];
    const float* b_ih     = (const float*)d_in[9];
    const float* b_hh     = (const float*)d_in[10];
    const float* word_emb = (const float*)d_in[11];

    float* out = (float*)d_out;        // [64*1024] hiddens, then [64] captions (as float)
    float* wsf = (float*)d_ws;
    float* h0 = wsf;
    float* h1 = wsf + 1024;
    float* c0 = wsf + 2048;
    float* c1 = wsf + 3072;
    float* xin = wsf + 4096;
    float* x0  = wsf + 6400;
    int*   wid_arr = (int*)(wsf + 6912);
    unsigned long long* partial = (unsigned long long*)((char*)d_ws + 27904);

    k_init<<<16, 256, 0, stream>>>(img_feat, uid, wei_user, wsf);
    k_x0<<<128, 256, 0, stream>>>(WI_w, WI_b, xin, x0);

    // prime step: h=c=0 (buf0) -> buf1
    k_lstm<<<256, 256, 0, stream>>>(-1, W_ih, W_hh, b_ih, b_hh, word_emb, x0, wid_arr,
                                    h0, c0, h1, c1, nullptr);

    for (int t = 0; t < CAP_LEN; ++t) {
        const float* hi = (t & 1) ? h0 : h1;
        const float* ci = (t & 1) ? c0 : c1;
        float* ho = (t & 1) ? h1 : h0;
        float* co = (t & 1) ? c1 : c0;
        k_lstm<<<256, 256, 0, stream>>>(t, W_ih, W_hh, b_ih, b_hh, word_emb, x0, wid_arr,
                                        hi, ci, ho, co, out + (size_t)t * H_DIM);
        k_logits<<<NBLK_LOGITS, 256, 0, stream>>>(WP_w, WP_b, ho, partial);
        k_argmax_reduce<<<1, 256, 0, stream>>>(partial, wid_arr, t, out + 65536);
    }
}

// Round 2
// 1327.103 us; speedup vs baseline: 1.4260x; 1.4260x over previous
//
#include <hip/hip_runtime.h>
#include <hip/hip_bf16.h>
#include <math.h>

#define H_DIM 1024
#define W_DIM 512
#define VOC 32000
#define CAP_LEN 64
#define U_DIM 256
#define IMG_DIM 2048
#define XIN_DIM (IMG_DIM + U_DIM)   // 2304
#define SOS 31998
#define NBLK_LOGITS 512              // partial-argmax blocks

// ---------------- ws layout ----------------
// floats: h0 @ 0, h1 @ 1024, c0 @ 2048, c1 @ 3072, xin @ 4096, x0 @ 6400
// bytes:  partial @ 27904 (512 u64)
// bytes:  WP16 @ 1 MiB (32000*1024 bf16 = 65.5 MB)  [only if ws_size permits]

__device__ __forceinline__ float wave_reduce_sum(float v) {
    #pragma unroll
    for (int off = 32; off > 0; off >>= 1)
        v += __shfl_xor(v, off, 64);
    return v;
}

__device__ __forceinline__ unsigned long long umax64(unsigned long long a, unsigned long long b) {
    return a > b ? a : b;
}

__device__ __forceinline__ unsigned short f2bf_rne(float f) {
    unsigned u = __float_as_uint(f);
    unsigned rounding = 0x7FFFu + ((u >> 16) & 1u);
    return (unsigned short)((u + rounding) >> 16);
}
__device__ __forceinline__ float bflo(unsigned u) { return __uint_as_float(u << 16); }
__device__ __forceinline__ float bfhi(unsigned u) { return __uint_as_float(u & 0xFFFF0000u); }

// zero h0/h1/c0/c1, build xin = concat(img_feat, wei_user[uid])
__global__ void k_init(const float* __restrict__ img, const int* __restrict__ uid,
                       const float* __restrict__ wei_user, float* __restrict__ wsf) {
    int i = blockIdx.x * blockDim.x + threadIdx.x;
    if (i < 4096) wsf[i] = 0.f;
    if (i < XIN_DIM) {
        float v = (i < IMG_DIM) ? img[i]
                                : wei_user[(size_t)uid[0] * U_DIM + (i - IMG_DIM)];
        wsf[4096 + i] = v;
    }
}

// WP_w f32 -> bf16 (RNE), 8 elems/thread
__global__ void k_cvt_wp(const float* __restrict__ src, ushort* __restrict__ dst) {
    int i = blockIdx.x * blockDim.x + threadIdx.x;   // i < 4096000
    const float4 a = reinterpret_cast<const float4*>(src)[2 * i];
    const float4 b = reinterpret_cast<const float4*>(src)[2 * i + 1];
    union { ushort s[8]; uint4 v; } u;
    u.s[0] = f2bf_rne(a.x); u.s[1] = f2bf_rne(a.y);
    u.s[2] = f2bf_rne(a.z); u.s[3] = f2bf_rne(a.w);
    u.s[4] = f2bf_rne(b.x); u.s[5] = f2bf_rne(b.y);
    u.s[6] = f2bf_rne(b.z); u.s[7] = f2bf_rne(b.w);
    reinterpret_cast<uint4*>(dst)[i] = u.v;
}

// x0 = WI_w @ xin + WI_b   (512 rows x 2304)
__global__ void k_x0(const float* __restrict__ WI_w, const float* __restrict__ WI_b,
                     const float* __restrict__ xin, float* __restrict__ x0) {
    int wave = threadIdx.x >> 6;
    int lane = threadIdx.x & 63;
    int row  = blockIdx.x * 4 + wave;          // grid 128 -> 512 rows
    const float* wr = WI_w + (size_t)row * XIN_DIM;
    float acc = 0.f;
    #pragma unroll
    for (int k = 0; k < 9; ++k) {
        int col = 4 * lane + 256 * k;
        float4 w4 = *reinterpret_cast<const float4*>(wr  + col);
        float4 v4 = *reinterpret_cast<const float4*>(xin + col);
        acc += w4.x * v4.x + w4.y * v4.y + w4.z * v4.z + w4.w * v4.w;
    }
    acc = wave_reduce_sum(acc);
    if (lane == 0) x0[row] = acc + WI_b[row];
}

// One LSTM step with fused argmax of the PREVIOUS step's logits partials.
// t = -1: prime (x = x0). t = 0: x = word_emb[SOS]. t >= 1: reduce partials ->
// wid_{t-1}; block 0 writes caption[t-1]; x = word_emb[wid].
__global__ void k_lstm(int t,
                       const float* __restrict__ W_ih, const float* __restrict__ W_hh,
                       const float* __restrict__ b_ih, const float* __restrict__ b_hh,
                       const float* __restrict__ word_emb, const float* __restrict__ x0,
                       const unsigned long long* __restrict__ partial,
                       float* __restrict__ out_cap,
                       const float* __restrict__ h_in, const float* __restrict__ c_in,
                       float* __restrict__ h_out, float* __restrict__ c_out,
                       float* __restrict__ out_hid) {
    __shared__ unsigned long long red[256];
    int tid  = threadIdx.x;
    int wave = tid >> 6;
    int lane = tid & 63;
    int j = blockIdx.x * 4 + wave;             // grid 256 -> 1024 elements

    const float* x;
    if (t < 0) {
        x = x0;
    } else if (t == 0) {
        x = word_emb + (size_t)SOS * W_DIM;
    } else {
        unsigned long long b = umax64(partial[tid], partial[tid + 256]);
        red[tid] = b;
        __syncthreads();
        #pragma unroll
        for (int s = 128; s >= 1; s >>= 1) {
            if (tid < s) red[tid] = umax64(red[tid], red[tid + s]);
            __syncthreads();
        }
        int wid = (int)(0xFFFFFFFFu - (unsigned)(red[0] & 0xFFFFFFFFull));
        if (blockIdx.x == 0 && tid == 0) out_cap[t - 1] = (float)wid;
        x = word_emb + (size_t)wid * W_DIM;
    }

    float g[4];
    #pragma unroll
    for (int gi = 0; gi < 4; ++gi) {
        int row = gi * H_DIM + j;
        const float* wi = W_ih + (size_t)row * W_DIM;
        const float* wh = W_hh + (size_t)row * H_DIM;
        float acc = 0.f;
        #pragma unroll
        for (int k = 0; k < 2; ++k) {
            int col = 4 * lane + 256 * k;
            float4 w4 = *reinterpret_cast<const float4*>(wi + col);
            float4 v4 = *reinterpret_cast<const float4*>(x  + col);
            acc += w4.x * v4.x + w4.y * v4.y + w4.z * v4.z + w4.w * v4.w;
        }
        #pragma unroll
        for (int k = 0; k < 4; ++k) {
            int col = 4 * lane + 256 * k;
            float4 w4 = *reinterpret_cast<const float4*>(wh   + col);
            float4 v4 = *reinterpret_cast<const float4*>(h_in + col);
            acc += w4.x * v4.x + w4.y * v4.y + w4.z * v4.z + w4.w * v4.w;
        }
        acc = wave_reduce_sum(acc);
        g[gi] = acc + b_ih[row] + b_hh[row];
    }
    if (lane == 0) {
        float ig = 1.f / (1.f + expf(-g[0]));
        float fg = 1.f / (1.f + expf(-g[1]));
        float gg = tanhf(g[2]);
        float og = 1.f / (1.f + expf(-g[3]));
        float cn = fg * c_in[j] + ig * gg;
        float hn = og * tanhf(cn);
        c_out[j] = cn;
        h_out[j] = hn;
        if (out_hid) out_hid[j] = hn;
    }
}

// bf16-weight logits + per-block partial argmax (packed key|~row)
__global__ void k_logits_bf16(const ushort* __restrict__ WP16,
                              const float* __restrict__ WP_b,
                              const float* __restrict__ h,
                              unsigned long long* __restrict__ partial) {
    int wave = threadIdx.x >> 6;
    int lane = threadIdx.x & 63;
    int wv = blockIdx.x * 4 + wave;            // 2048 waves
    // this lane's h slice: elems [8*lane, 8*lane+8) and [512+8*lane, ...)
    float4 h0a = *reinterpret_cast<const float4*>(h + 8 * lane);
    float4 h0b = *reinterpret_cast<const float4*>(h + 8 * lane + 4);
    float4 h1a = *reinterpret_cast<const float4*>(h + 8 * lane + 512);
    float4 h1b = *reinterpret_cast<const float4*>(h + 8 * lane + 516);
    unsigned long long best = 0ull;
    for (int row = wv; row < VOC; row += NBLK_LOGITS * 4) {
        const uint4* wr = reinterpret_cast<const uint4*>(WP16 + (size_t)row * H_DIM);
        uint4 w0 = wr[lane];
        uint4 w1 = wr[lane + 64];
        float acc;
        acc  = bflo(w0.x) * h0a.x + bfhi(w0.x) * h0a.y;
        acc += bflo(w0.y) * h0a.z + bfhi(w0.y) * h0a.w;
        acc += bflo(w0.z) * h0b.x + bfhi(w0.z) * h0b.y;
        acc += bflo(w0.w) * h0b.z + bfhi(w0.w) * h0b.w;
        acc += bflo(w1.x) * h1a.x + bfhi(w1.x) * h1a.y;
        acc += bflo(w1.y) * h1a.z + bfhi(w1.y) * h1a.w;
        acc += bflo(w1.z) * h1b.x + bfhi(w1.z) * h1b.y;
        acc += bflo(w1.w) * h1b.z + bfhi(w1.w) * h1b.w;
        acc = wave_reduce_sum(acc);
        float logit = acc + WP_b[row];
        unsigned int ub = __float_as_uint(logit);
        ub = (ub & 0x80000000u) ? ~ub : (ub | 0x80000000u);
        unsigned long long p = ((unsigned long long)ub << 32)
                             | (unsigned long long)(0xFFFFFFFFu - (unsigned)row);
        best = umax64(best, p);
    }
    __shared__ unsigned long long sm[4];
    if (lane == 0) sm[wave] = best;
    __syncthreads();
    if (threadIdx.x == 0) {
        unsigned long long m = umax64(umax64(sm[0], sm[1]), umax64(sm[2], sm[3]));
        partial[blockIdx.x] = m;
    }
}

// f32 fallback logits (if ws too small for WP16)
__global__ void k_logits_f32(const float* __restrict__ WP_w, const float* __restrict__ WP_b,
                             const float* __restrict__ h,
                             unsigned long long* __restrict__ partial) {
    int wave = threadIdx.x >> 6;
    int lane = threadIdx.x & 63;
    int wv = blockIdx.x * 4 + wave;
    unsigned long long best = 0ull;
    for (int row = wv; row < VOC; row += NBLK_LOGITS * 4) {
        const float* wr = WP_w + (size_t)row * H_DIM;
        float acc = 0.f;
        #pragma unroll
        for (int k = 0; k < 4; ++k) {
            int col = 4 * lane + 256 * k;
            float4 w4 = *reinterpret_cast<const float4*>(wr + col);
            float4 v4 = *reinterpret_cast<const float4*>(h  + col);
            acc += w4.x * v4.x + w4.y * v4.y + w4.z * v4.z + w4.w * v4.w;
        }
        acc = wave_reduce_sum(acc);
        float logit = acc + WP_b[row];
        unsigned int ub = __float_as_uint(logit);
        ub = (ub & 0x80000000u) ? ~ub : (ub | 0x80000000u);
        unsigned long long p = ((unsigned long long)ub << 32)
                             | (unsigned long long)(0xFFFFFFFFu - (unsigned)row);
        best = umax64(best, p);
    }
    __shared__ unsigned long long sm[4];
    if (lane == 0) sm[wave] = best;
    __syncthreads();
    if (threadIdx.x == 0) {
        unsigned long long m = umax64(umax64(sm[0], sm[1]), umax64(sm[2], sm[3]));
        partial[blockIdx.x] = m;
    }
}

// final caption (t = 63) from partials
__global__ void k_argmax_final(const unsigned long long* __restrict__ partial,
                               float* __restrict__ out_cap) {
    __shared__ unsigned long long sm[256];
    int tid = threadIdx.x;
    sm[tid] = umax64(partial[tid], partial[tid + 256]);
    __syncthreads();
    for (int s = 128; s > 0; s >>= 1) {
        if (tid < s) sm[tid] = umax64(sm[tid], sm[tid + s]);
        __syncthreads();
    }
    if (tid == 0) {
        int row = (int)(0xFFFFFFFFu - (unsigned)(sm[0] & 0xFFFFFFFFull));
        out_cap[CAP_LEN - 1] = (float)row;
    }
}

extern "C" void kernel_launch(void* const* d_in, const int* in_sizes, int n_in,
                              void* d_out, int out_size, void* d_ws, size_t ws_size,
                              hipStream_t stream) {
    const float* img_feat = (const float*)d_in[0];
    const int*   uid      = (const int*)  d_in[1];
    const float* wei_user = (const float*)d_in[2];
    const float* WI_w     = (const float*)d_in[3];
    const float* WI_b     = (const float*)d_in[4];
    const float* WP_w     = (const float*)d_in[5];
    const float* WP_b     = (const float*)d_in[6];
    const float* W_ih     = (const float*)d_in[7];
    const float* W_hh     = (const float*)d_in[8];
    const float* b_ih     = (const float*)d_in[9];
    const float* b_hh     = (const float*)d_in[10];
    const float* word_emb = (const float*)d_in[11];

    float* out = (float*)d_out;        // [64*1024] hiddens, then [64] captions (as float)
    float* wsf = (float*)d_ws;
    float* h0 = wsf;
    float* h1 = wsf + 1024;
    float* c0 = wsf + 2048;
    float* c1 = wsf + 3072;
    float* xin = wsf + 4096;
    float* x0  = wsf + 6400;
    unsigned long long* partial = (unsigned long long*)((char*)d_ws + 27904);
    ushort* WP16 = (ushort*)((char*)d_ws + (1 << 20));
    const size_t wp16_need = (1u << 20) + (size_t)VOC * H_DIM * sizeof(ushort);
    const bool use_bf16 = ws_size >= wp16_need;

    if (use_bf16)
        k_cvt_wp<<<16000, 256, 0, stream>>>(WP_w, WP16);   // 32000*1024/8 threads
    k_init<<<16, 256, 0, stream>>>(img_feat, uid, wei_user, wsf);
    k_x0<<<128, 256, 0, stream>>>(WI_w, WI_b, xin, x0);

    float* out_cap = out + CAP_LEN * H_DIM;

    // prime step: h=c=0 (buf0) -> buf1
    k_lstm<<<256, 256, 0, stream>>>(-1, W_ih, W_hh, b_ih, b_hh, word_emb, x0,
                                    partial, out_cap, h0, c0, h1, c1, nullptr);

    for (int t = 0; t < CAP_LEN; ++t) {
        const float* hi = (t & 1) ? h0 : h1;
        const float* ci = (t & 1) ? c0 : c1;
        float* ho = (t & 1) ? h1 : h0;
        float* co = (t & 1) ? c1 : c0;
        k_lstm<<<256, 256, 0, stream>>>(t, W_ih, W_hh, b_ih, b_hh, word_emb, x0,
                                        partial, out_cap, hi, ci, ho, co,
                                        out + (size_t)t * H_DIM);
        if (use_bf16)
            k_logits_bf16<<<NBLK_LOGITS, 256, 0, stream>>>(WP16, WP_b, ho, partial);
        else
            k_logits_f32<<<NBLK_LOGITS, 256, 0, stream>>>(WP_w, WP_b, ho, partial);
    }
    k_argmax_final<<<1, 256, 0, stream>>>(partial, out_cap);
}